// Round 1
// 54.464 us; speedup vs baseline: 1.6412x; 1.6412x over previous
//
#include <hip/hip_runtime.h>
#include <math.h>

#define NBATCH 16
#define NATOM  512
#define NEIGH  64
#define PPM    (NATOM * NEIGH)      // 32768 = 2^15
#define NPAIR  (NBATCH * PPM)       // 524288
#define TOTATOM (NBATCH * NATOM)    // 8192
#define NTYPE  4
#define NWAVE  8
#define MAXN   128                  // slot capacity per atom (avg count = 64, P(overflow) ~ 1e-7)
#define PI_OVER_CUTOFF 0.6283185307179586f

// ---- workspace layout (bytes) ----
// cursors : int[8192]                      @ 0        (32 KB)
// records : float4[TOTATOM * MAXN] (16 MB) @ 32768
#define WS_OFF_RECORDS 32768

// Zero the per-atom cursors. Custom kernel instead of hipMemsetAsync:
// the rocprof trace showed the 32 KB fillBufferAligned node costing ~40 us.
__global__ __launch_bounds__(256) void zero_kernel(int* __restrict__ cursors)
{
    int gid = blockIdx.x * 256 + threadIdx.x;   // grid = 32 * 256 = 8192
    cursors[gid] = 0;
}

// One pass over all pairs: claim a fixed-stride slot via atomic cursor and
// write the precomputed record (dx, dy, dz, species). No count/scan needed.
__global__ __launch_bounds__(256) void scatter_kernel(
    const int* __restrict__ atom_index, const float* __restrict__ shifts,
    const float* __restrict__ cart, const int* __restrict__ species,
    int* __restrict__ cursors, float4* __restrict__ records)
{
    int gid = blockIdx.x * 256 + threadIdx.x;   // grid = NPAIR/256 = 2048 blocks, exact
    float s0 = shifts[gid * 3 + 0];
    float s1 = shifts[gid * 3 + 1];
    float s2 = shifts[gid * 3 + 2];
    if (!(s0 > -1e10f && s1 > -1e10f && s2 > -1e10f)) return;
    int b  = gid >> 15;                          // PPM = 2^15
    int i0 = atom_index[gid] + b * NATOM;
    int i1 = atom_index[NPAIR + gid] + b * NATOM;
    int pos = atomicAdd(&cursors[i0], 1);
    if (pos >= MAXN) return;                     // memory-safety clamp (never hit for this input)
    float dx = cart[i0 * 3 + 0] - cart[i1 * 3 + 0] + s0;
    float dy = cart[i0 * 3 + 1] - cart[i1 * 3 + 1] + s1;
    float dz = cart[i0 * 3 + 2] - cart[i1 * 3 + 2] + s2;
    int sp = species[i1];
    records[i0 * MAXN + pos] = make_float4(dx, dy, dz, __int_as_float(sp));
}

__global__ __launch_bounds__(256) void density_kernel(
    const float4* __restrict__ records, const int* __restrict__ cursors,
    const float* __restrict__ rs, const float* __restrict__ inta,
    const float* __restrict__ params, float* __restrict__ out)
{
    __shared__ float s_rs[NTYPE * NWAVE];
    __shared__ float s_ia[NTYPE * NWAVE];
    __shared__ float s_pm[NTYPE * NWAVE];
    if (threadIdx.x < NTYPE * NWAVE) {
        s_rs[threadIdx.x] = rs[threadIdx.x];
        s_ia[threadIdx.x] = inta[threadIdx.x];
        s_pm[threadIdx.x] = params[threadIdx.x];
    }
    __syncthreads();

    int atom = blockIdx.x * 4 + (threadIdx.x >> 6);  // grid = TOTATOM/4 = 2048
    int lane = threadIdx.x & 63;
    int w    = lane & 7;        // basis index
    int rsub = lane >> 3;       // record subset 0..7

    int n = cursors[atom];
    if (n > MAXN) n = MAXN;
    const float4* rec = records + (size_t)atom * MAXN;

    float a0 = 0.f, a1 = 0.f, a2 = 0.f, a3 = 0.f, a4 = 0.f;
    float a5 = 0.f, a6 = 0.f, a7 = 0.f, a8 = 0.f, a9 = 0.f;

    for (int k = rsub; k < n; k += 8) {
        float4 r = rec[k];
        float dx = r.x, dy = r.y, dz = r.z;
        int sp = __float_as_int(r.w);
        float d2 = dx * dx + dy * dy + dz * dz;
        float d  = sqrtf(d2);
        float c  = 0.5f * cosf(d * PI_OVER_CUTOFF) + 0.5f;
        float fc = c * c;
        int ti = sp * NWAVE + w;
        float t = d - s_rs[ti];
        float g = fc * s_pm[ti] * expf(-s_ia[ti] * t * t);
        a0 += g;
        a1 += g * dx; a2 += g * dy; a3 += g * dz;
        a4 += g * dx * dx; a5 += g * dx * dy; a6 += g * dx * dz;
        a7 += g * dy * dy; a8 += g * dy * dz; a9 += g * dz * dz;
    }

#define RED(v) { v += __shfl_xor(v, 8); v += __shfl_xor(v, 16); v += __shfl_xor(v, 32); }
    RED(a0) RED(a1) RED(a2) RED(a3) RED(a4)
    RED(a5) RED(a6) RED(a7) RED(a8) RED(a9)
#undef RED

    if (rsub == 0) {
        float* o = out + (size_t)atom * 24;
        o[w]      = a0 * a0;
        o[8 + w]  = a1 * a1 + a2 * a2 + a3 * a3;
        o[16 + w] = a4 * a4 + a7 * a7 + a9 * a9
                  + 2.0f * (a5 * a5 + a6 * a6 + a8 * a8);
    }
}

extern "C" void kernel_launch(void* const* d_in, const int* in_sizes, int n_in,
                              void* d_out, int out_size, void* d_ws, size_t ws_size,
                              hipStream_t stream)
{
    const float* cart      = (const float*)d_in[0];
    // d_in[1] = numatoms (unused by reference math)
    const int*   species   = (const int*)d_in[2];
    const int*   atom_index= (const int*)d_in[3];
    const float* shifts    = (const float*)d_in[4];
    const float* rs        = (const float*)d_in[5];
    const float* inta      = (const float*)d_in[6];
    const float* params    = (const float*)d_in[7];
    float* out = (float*)d_out;

    char* ws = (char*)d_ws;
    int*    cursors = (int*)ws;
    float4* records = (float4*)(ws + WS_OFF_RECORDS);

    zero_kernel<<<TOTATOM / 256, 256, 0, stream>>>(cursors);
    scatter_kernel<<<NPAIR / 256, 256, 0, stream>>>(
        atom_index, shifts, cart, species, cursors, records);
    density_kernel<<<TOTATOM / 4, 256, 0, stream>>>(
        records, cursors, rs, inta, params, out);
}